// Round 3
// baseline (6796.527 us; speedup 1.0000x reference)
//
#include <hip/hip_runtime.h>
#include <hip/hip_bf16.h>

#define Bz 32
#define Tz 1024
#define Iz 64
#define Hz 512
#define Az 16
#define NBLK 4   // 2 pairs; pair p = rows [16p,16p+16); block qh in pair owns cols [256qh,256qh+256)

// d_out layout (FP32 elems): out [B,T,A] | hn [1,B,H] | rnn_out [B,T,H]
#define OFF_HN  (Bz*Tz*Az)
#define OFF_RNN (OFF_HN + Bz*Hz)

typedef unsigned short u16;
typedef unsigned int u32;
typedef unsigned long long u64;
typedef __attribute__((ext_vector_type(8))) unsigned short u16x8;
typedef __attribute__((ext_vector_type(8))) __bf16 bf16x8;
typedef __attribute__((ext_vector_type(4))) float f32x4;

// ws layout (bytes)
#define WS_FLAGS 0x00000u   // int[1025*NBLK] = 16,400 B (zeroed each launch)
#define WS_RING  0x21000u   // u16[4][32][512] = 131072 B
#define WS_WHH   0x41000u   // u16[512*512] bf16 = 512 KB
#define WS_WIH   0xC1000u   // u16[64*512] bf16 = 64 KB
#define WS_W1T   0xD1000u   // u16[512*512] bf16 [n][k]
#define WS_ZERO  0x11000u   // memset span: covers flags only

__device__ __forceinline__ u16 f2bf(float f) {
  union { float f; unsigned int i; } x; x.f = f;
  unsigned int r = (x.i + 0x7FFFu + ((x.i >> 16) & 1u)) >> 16;
  return (u16)r;
}
__device__ __forceinline__ float bf2f(u16 u) {
  union { unsigned int i; float f; } x; x.i = ((unsigned int)u) << 16; return x.f;
}
__device__ __forceinline__ float sigmoidf_(float z) {
  return 1.0f / (1.0f + __expf(-z));
}

// ---------------------------------------------------------------------------
// Prep: fp32 -> bf16 copies (w_hh, w_ih layout-preserved; fc1_w transposed)
// ---------------------------------------------------------------------------
__global__ void prep_kernel(const float* __restrict__ whh,
                            const float* __restrict__ wih,
                            const float* __restrict__ w1,
                            u16* __restrict__ whh_bf,
                            u16* __restrict__ wih_bf,
                            u16* __restrict__ w1t_bf) {
  int idx = blockIdx.x * 256 + threadIdx.x;
  if (idx < 262144) {
    whh_bf[idx] = f2bf(whh[idx]);
  } else if (idx < 294912) {
    int i = idx - 262144;
    wih_bf[i] = f2bf(wih[i]);
  } else if (idx < 557056) {
    int j = idx - 294912;
    int n = j >> 9, k = j & 511;
    w1t_bf[n * Hz + k] = f2bf(w1[k * Hz + n]);  // [n][k] <- [k][n]
  }
}

// ---------------------------------------------------------------------------
// Scan R9 (batch-split pairs): 4 blocks x 512 thr (8 waves).
// The recurrence is batch-row independent: h[b,:] never reads h[b',:].
// Pair p = rows [16p,16p+16); within a pair, block qh owns cols
// [256qh, 256qh+256) and holds W_hh[:, own-cols] fully in registers
// (128 VGPR/wave of bf16 B-frags). Per step only an 8 KB h-half is
// exchanged with ONE partner block (flags fan-in = 1).
//   - own-half K MFMAs read A-frags from LDS (written locally last step),
//     and execute BEFORE the partner poll (hides compute under exchange).
//   - partner-half K MFMAs read A-frags DIRECTLY from the coherent ring
//     (16 u64 relaxed agent loads -> one pipelined L3 round trip).
// Protocol (proven, unchanged): producer ring atomic-stores -> __syncthreads
// (drains own vmcnt; stores at coherence point) -> relaxed flag store ->
// plain output stores. Consumer: relaxed flag poll (exit only after load
// RETURNS 1) -> coherent loads issued strictly later.
// MFMA 16x16x32 bf16 (HW-proven): A m=lane&15,k=q*8+j; B n=lane&15,k=q*8+j;
//                                 C/D col=lane&15, row=q*4+reg.
// Ring depth 4 + flag lockstep (partner >= t-1 when we write slot (t+1)&3)
// keeps slot reuse race-free (same argument as prior rounds).
// ---------------------------------------------------------------------------
__global__ __launch_bounds__(512, 2) void rnn_scan_kernel(
    const float* __restrict__ inp,   // [B][T][I] fp32
    const float* __restrict__ hn,    // [B][H] fp32
    const u16* __restrict__ whh_bf,  // [k=H][n=H] bf16
    const u16* __restrict__ wih_bf,  // [i=I][n=H] bf16
    float* __restrict__ out_rnn,     // [B][T][H] fp32
    float* __restrict__ out_hn,      // [B][H] fp32
    int* __restrict__ flags,         // [1025][NBLK] (zeroed)
    u16* __restrict__ hbuf)          // [4][B][H] bf16 ring
{
  // own-half h, double-buffered. Row stride 264 u16 = 528 B (multiple of 16
  // for ds_read_b128; +8 pad gives 4-bank/row shift to spread b128 groups).
  __shared__ u16 hlds[2][16][264];

  const int tid  = threadIdx.x;
  const int lane = tid & 63;
  const int w    = tid >> 6;        // wave 0..7 -> own cols [32w, 32w+32)
  const int ln   = lane & 15;
  const int q    = lane >> 4;
  const int bid  = blockIdx.x;
  const int qh   = bid & 1;         // col-half within pair
  const int p    = bid >> 1;        // pair index (row group)
  const int r0   = p * 16;          // global row base
  const int cbase = qh * 256;       // own col base
  const int obase = (1 - qh) * 256; // partner col base
  const int c0   = cbase + w * 32;  // wave's own col base
  const int partner = bid ^ 1;

  // ---- Preload W_hh B-frags for own cols, ALL K (ks 0..7 own-half K,
  // ks 8..15 partner-half K) : 2 tiles x 16 K-steps x 4 VGPR = 128 VGPR.
  bf16x8 bhh[2][16];
#pragma unroll
  for (int ct = 0; ct < 2; ++ct)
#pragma unroll
    for (int ks = 0; ks < 16; ++ks) {
      const int kg = (ks < 8) ? (cbase + ks * 32) : (obase + (ks - 8) * 32);
      u16x8 f;
#pragma unroll
      for (int j = 0; j < 8; ++j)
        f[j] = whh_bf[(kg + q * 8 + j) * Hz + c0 + ct * 16 + ln];
      bhh[ct][ks] = __builtin_bit_cast(bf16x8, f);
    }

  // ---- W_ih B-frags: 2 tiles x 2 K-steps (I=64)
  bf16x8 bih[2][2];
#pragma unroll
  for (int ct = 0; ct < 2; ++ct)
#pragma unroll
    for (int kc = 0; kc < 2; ++kc) {
      u16x8 f;
#pragma unroll
      for (int j = 0; j < 8; ++j)
        f[j] = wih_bf[(kc * 32 + q * 8 + j) * Hz + c0 + ct * 16 + ln];
      bih[ct][kc] = __builtin_bit_cast(bf16x8, f);
    }

  // ---- Init: h0 (own rows x own cols) -> LDS buf0 + ring slot 0
  {
    const int lrow = tid >> 5;          // 0..15
    const int cc   = (tid & 31) * 8;    // 0..248
    f32x4 a = *(const f32x4*)(hn + (size_t)(r0 + lrow) * Hz + cbase + cc);
    f32x4 b = *(const f32x4*)(hn + (size_t)(r0 + lrow) * Hz + cbase + cc + 4);
    u16x8 px;
#pragma unroll
    for (int j = 0; j < 4; ++j) { px[j] = f2bf(a[j]); px[4 + j] = f2bf(b[j]); }
    *(u16x8*)&hlds[0][lrow][cc] = px;
    u32* rp = (u32*)(hbuf + (size_t)(r0 + lrow) * Hz + cbase + cc);
#pragma unroll
    for (int k = 0; k < 4; ++k) {
      u32 pk = (u32)px[2 * k] | ((u32)px[2 * k + 1] << 16);
      __hip_atomic_store(rp + k, pk, __ATOMIC_RELAXED, __HIP_MEMORY_SCOPE_AGENT);
    }
  }
  __syncthreads();
  if (tid == 0)
    __hip_atomic_store(&flags[bid], 1, __ATOMIC_RELAXED,
                       __HIP_MEMORY_SCOPE_AGENT);

  for (int t = 0; t < Tz; ++t) {
    const int cur = t & 1;

    // inp loads for this step (HBM/L2, issued early)
    const float* ip = inp + ((size_t)(r0 + ln) * Tz + t) * Iz + q * 8;
    f32x4 x0 = *(const f32x4*)(ip);
    f32x4 x1 = *(const f32x4*)(ip + 4);
    f32x4 x2 = *(const f32x4*)(ip + 32);
    f32x4 x3 = *(const f32x4*)(ip + 36);
    u16x8 ax0, ax1;
#pragma unroll
    for (int j = 0; j < 4; ++j) {
      ax0[j]     = f2bf(x0[j]);
      ax0[4 + j] = f2bf(x1[j]);
      ax1[j]     = f2bf(x2[j]);
      ax1[4 + j] = f2bf(x3[j]);
    }

    f32x4 acc[2];
    acc[0] = (f32x4){0.f, 0.f, 0.f, 0.f};
    acc[1] = (f32x4){0.f, 0.f, 0.f, 0.f};

    // x-projection MFMAs
#pragma unroll
    for (int ct = 0; ct < 2; ++ct) {
      acc[ct] = __builtin_amdgcn_mfma_f32_16x16x32_bf16(
          __builtin_bit_cast(bf16x8, ax0), bih[ct][0], acc[ct], 0, 0, 0);
      acc[ct] = __builtin_amdgcn_mfma_f32_16x16x32_bf16(
          __builtin_bit_cast(bf16x8, ax1), bih[ct][1], acc[ct], 0, 0, 0);
    }

    // Phase A: own-half K from LDS (pre-poll; hides under partner exchange)
#pragma unroll
    for (int ks = 0; ks < 8; ++ks) {
      bf16x8 afr = __builtin_bit_cast(
          bf16x8, *(const u16x8*)&hlds[cur][ln][ks * 32 + q * 8]);
#pragma unroll
      for (int ct = 0; ct < 2; ++ct)
        acc[ct] = __builtin_amdgcn_mfma_f32_16x16x32_bf16(
            afr, bhh[ct][ks], acc[ct], 0, 0, 0);
    }

    // Poll single partner flag (wave-uniform address, all waves)
    {
      int got;
      do {
        got = __hip_atomic_load(&flags[t * NBLK + partner], __ATOMIC_RELAXED,
                                __HIP_MEMORY_SCOPE_AGENT);
      } while (!got);
    }

    // Phase B: partner-half A-frags straight from the coherent ring
    const u64* pb = (const u64*)hbuf + (size_t)(t & 3) * (Bz * Hz / 4) +
                    (size_t)(r0 + ln) * (Hz / 4) + (obase / 4);
    u64 hr[16];
#pragma unroll
    for (int ks2 = 0; ks2 < 8; ++ks2) {
      hr[2 * ks2]     = __hip_atomic_load(pb + ks2 * 8 + q * 2,
                                          __ATOMIC_RELAXED,
                                          __HIP_MEMORY_SCOPE_AGENT);
      hr[2 * ks2 + 1] = __hip_atomic_load(pb + ks2 * 8 + q * 2 + 1,
                                          __ATOMIC_RELAXED,
                                          __HIP_MEMORY_SCOPE_AGENT);
    }
#pragma unroll
    for (int ks2 = 0; ks2 < 8; ++ks2) {
      u64 v[2] = {hr[2 * ks2], hr[2 * ks2 + 1]};
      bf16x8 afr = __builtin_bit_cast(bf16x8, v);
#pragma unroll
      for (int ct = 0; ct < 2; ++ct)
        acc[ct] = __builtin_amdgcn_mfma_f32_16x16x32_bf16(
            afr, bhh[ct][8 + ks2], acc[ct], 0, 0, 0);
    }

    // Epilogue: sigmoid; pack pairs; ring store + LDS store (next buffer)
    const int nxt = cur ^ 1;
    u16* ring_next = hbuf + (size_t)((t + 1) & 3) * (Bz * Hz);
    float hv[2][4];
#pragma unroll
    for (int ct = 0; ct < 2; ++ct)
#pragma unroll
      for (int r = 0; r < 4; ++r) {
        hv[ct][r] = sigmoidf_(acc[ct][r]);
        u32 mine  = (u32)f2bf(hv[ct][r]);
        u32 other = (u32)__shfl_xor((int)mine, 1, 64);
        if (!(ln & 1)) {
          u32 pk = mine | (other << 16);
          const int lrow = q * 4 + r;
          const int lcol = w * 32 + ct * 16 + ln;  // within own 256-col half
          __hip_atomic_store(
              (u32*)(ring_next + (size_t)(r0 + lrow) * Hz + cbase + lcol), pk,
              __ATOMIC_RELAXED, __HIP_MEMORY_SCOPE_AGENT);
          *(u32*)&hlds[nxt][lrow][lcol] = pk;
        }
      }
    __syncthreads();  // drains every thread's ring/LDS stores before flag
    if (tid == 0)
      __hip_atomic_store(&flags[(t + 1) * NBLK + bid], 1, __ATOMIC_RELAXED,
                         __HIP_MEMORY_SCOPE_AGENT);

    // Output stores AFTER the flag release — off the critical path
#pragma unroll
    for (int ct = 0; ct < 2; ++ct)
#pragma unroll
      for (int r = 0; r < 4; ++r) {
        const int grow = r0 + q * 4 + r;
        const int gcol = c0 + ct * 16 + ln;
        out_rnn[((size_t)grow * Tz + t) * Hz + gcol] = hv[ct][r];
        if (t == Tz - 1) out_hn[(size_t)grow * Hz + gcol] = hv[ct][r];
      }
  }
}

// ---------------------------------------------------------------------------
// FC head (unchanged, R3-lineage): 256 blocks x 256 thr; fc1 MFMA bf16
// (tile 128x128, BK=64); hidden via LDS; fc2 VALU-accumulated; fp32 in/out.
// ---------------------------------------------------------------------------
__global__ __launch_bounds__(256, 2) void fc_kernel(
    const float* __restrict__ X,  // [32768][512] fp32 (= rnn_out)
    const u16* __restrict__ w1t,  // [n=512][k=512] bf16
    const float* __restrict__ b1, // [512] fp32
    const float* __restrict__ w2, // [n=512][a=16] fp32
    const float* __restrict__ b2, // [16] fp32
    float* __restrict__ out)      // [32768][16] fp32
{
  __shared__ u16 smem[18432];     // 36 KB
  u16* As = smem;                 // [128][72]
  u16* Bs = smem + 9216;          // [128][72]
  u16* Ht = smem;                 // [128][136] (reused, 34816 B)

  const int tid  = threadIdx.x;
  const int lane = tid & 63;
  const int wv   = tid >> 6;
  const int ln   = lane & 15, q = lane >> 4;
  const int mq   = (wv & 1) * 64, nq = (wv >> 1) * 64;
  const size_t r0 = (size_t)blockIdx.x * 128;
  const int om = tid >> 1;          // output row 0..127
  const int oa = (tid & 1) * 8;     // output col half

  float oacc[8];
#pragma unroll
  for (int j = 0; j < 8; ++j) oacc[j] = 0.f;

  for (int nt = 0; nt < 4; ++nt) {
    const int n0 = nt * 128;
    f32x4 acc[4][4];
#pragma unroll
    for (int mi = 0; mi < 4; ++mi)
#pragma unroll
      for (int ni = 0; ni < 4; ++ni) acc[mi][ni] = (f32x4){0.f, 0.f, 0.f, 0.f};

    for (int kb = 0; kb < 8; ++kb) {
      const int K0 = kb * 64;
      __syncthreads();  // prior frag/Ht reads done before restaging
      for (int i = tid; i < 1024; i += 256) {
        int row = i >> 3, c = (i & 7) * 8;
        f32x4 lo = *(const f32x4*)(X + (r0 + row) * Hz + K0 + c);
        f32x4 hi = *(const f32x4*)(X + (r0 + row) * Hz + K0 + c + 4);
        u16x8 pxx;
#pragma unroll
        for (int j = 0; j < 4; ++j) { pxx[j] = f2bf(lo[j]); pxx[4 + j] = f2bf(hi[j]); }
        *(u16x8*)(As + row * 72 + c) = pxx;
      }
      for (int i = tid; i < 1024; i += 256) {
        int row = i >> 3, c = (i & 7) * 8;
        *(u16x8*)(Bs + row * 72 + c) =
            *(const u16x8*)(w1t + (size_t)(n0 + row) * Hz + K0 + c);
      }
      __syncthreads();
#pragma unroll
      for (int kt = 0; kt < 2; ++kt) {
        bf16x8 af[4], bfr[4];
#pragma unroll
        for (int mi = 0; mi < 4; ++mi)
          af[mi] = __builtin_bit_cast(
              bf16x8,
              *(const u16x8*)(As + (mq + mi * 16 + ln) * 72 + kt * 32 + q * 8));
#pragma unroll
        for (int ni = 0; ni < 4; ++ni)
          bfr[ni] = __builtin_bit_cast(
              bf16x8,
              *(const u16x8*)(Bs + (nq + ni * 16 + ln) * 72 + kt * 32 + q * 8));
#pragma unroll
        for (int mi = 0; mi < 4; ++mi)
#pragma unroll
          for (int ni = 0; ni < 4; ++ni)
            acc[mi][ni] = __builtin_amdgcn_mfma_f32_16x16x32_bf16(
                af[mi], bfr[ni], acc[mi][ni], 0, 0, 0);
      }
    }
    __syncthreads();  // MFMA frag reads done before Ht overwrite

    // hidden = relu(acc + b1) -> Ht bf16
#pragma unroll
    for (int ni = 0; ni < 4; ++ni) {
      float bb = b1[n0 + nq + ni * 16 + ln];
#pragma unroll
      for (int mi = 0; mi < 4; ++mi)
#pragma unroll
        for (int r = 0; r < 4; ++r) {
          float h = fmaxf(acc[mi][ni][r] + bb, 0.f);
          Ht[(mq + mi * 16 + q * 4 + r) * 136 + nq + ni * 16 + ln] = f2bf(h);
        }
    }
    __syncthreads();

    // fc2 partial over this n-slice into registers
    for (int n = 0; n < 128; ++n) {
      float hv = bf2f(Ht[om * 136 + n]);
      const float* w2p = w2 + (size_t)(n0 + n) * Az + oa;
#pragma unroll
      for (int j = 0; j < 8; ++j) oacc[j] += hv * w2p[j];
    }
  }

#pragma unroll
  for (int j = 0; j < 8; ++j)
    out[(r0 + om) * Az + oa + j] = sigmoidf_(oacc[j] + b2[oa + j]);
}

extern "C" void kernel_launch(void* const* d_in, const int* in_sizes, int n_in,
                              void* d_out, int out_size, void* d_ws, size_t ws_size,
                              hipStream_t stream) {
  // Permutation detection from in_sizes (insurance; proven harmless R6/R7)
  int idx_inp = 0, idx_hn = 1, idx_wih = 3, idx_b1 = 5, idx_w2 = 6, idx_b2 = 7;
  int amb1 = -1, amb2 = -1, found = 0;
  for (int i = 0; i < 8 && i < n_in; ++i) {
    switch (in_sizes[i]) {
      case 2097152: idx_inp = i; found |= 1; break;
      case 16384:   idx_hn  = i; found |= 2; break;
      case 32768:   idx_wih = i; found |= 4; break;
      case 512:     idx_b1  = i; found |= 8; break;
      case 8192:    idx_w2  = i; found |= 16; break;
      case 16:      idx_b2  = i; found |= 32; break;
      case 262144:  if (amb1 < 0) amb1 = i; else amb2 = i; break;
    }
  }
  int idx_whh = 2, idx_w1 = 4;  // dict-order fallback
  if (amb1 >= 0 && amb2 >= 0 && found == 63) {
    if (idx_b1 < idx_inp) { idx_w1 = amb1; idx_whh = amb2; }
    else                  { idx_whh = amb1; idx_w1 = amb2; }
  }

  const float* inp = (const float*)d_in[idx_inp];
  const float* hn  = (const float*)d_in[idx_hn];
  const float* whh = (const float*)d_in[idx_whh];
  const float* wih = (const float*)d_in[idx_wih];
  const float* w1  = (const float*)d_in[idx_w1];
  const float* b1  = (const float*)d_in[idx_b1];
  const float* w2  = (const float*)d_in[idx_w2];
  const float* b2  = (const float*)d_in[idx_b2];

  float* out     = (float*)d_out;
  float* out_hn  = out + OFF_HN;
  float* out_rnn = out + OFF_RNN;

  char* ws    = (char*)d_ws;
  int* flags  = (int*)(ws + WS_FLAGS);
  u16* hbuf   = (u16*)(ws + WS_RING);
  u16* whh_bf = (u16*)(ws + WS_WHH);
  u16* wih_bf = (u16*)(ws + WS_WIH);
  u16* w1t_bf = (u16*)(ws + WS_W1T);

  (void)hipMemsetAsync(d_ws, 0, WS_ZERO, stream);
  prep_kernel<<<dim3(2176), dim3(256), 0, stream>>>(whh, wih, w1,
                                                    whh_bf, wih_bf, w1t_bf);
  rnn_scan_kernel<<<dim3(NBLK), dim3(512), 0, stream>>>(
      inp, hn, whh_bf, wih_bf, out_rnn, out_hn, flags, hbuf);
  fc_kernel<<<dim3(256), dim3(256), 0, stream>>>(
      out_rnn, w1t_bf, b1, w2, b2, out);
}

// Round 4
// 6796.497 us; speedup vs baseline: 1.0000x; 1.0000x over previous
//
#include <hip/hip_runtime.h>
#include <hip/hip_bf16.h>

#define Bz 32
#define Tz 1024
#define Iz 64
#define Hz 512
#define Az 16
#define NBLK 4   // 2 pairs; pair p = rows [16p,16p+16); block qh in pair owns cols [256qh,256qh+256)

// d_out layout (FP32 elems): out [B,T,A] | hn [1,B,H] | rnn_out [B,T,H]
#define OFF_HN  (Bz*Tz*Az)
#define OFF_RNN (OFF_HN + Bz*Hz)

typedef unsigned short u16;
typedef unsigned int u32;
typedef unsigned long long u64;
typedef __attribute__((ext_vector_type(8))) unsigned short u16x8;
typedef __attribute__((ext_vector_type(8))) __bf16 bf16x8;
typedef __attribute__((ext_vector_type(4))) float f32x4;

// ws layout (bytes)
#define WS_FLAGS 0x00000u   // int[1025*NBLK] = 16,400 B (zeroed each launch)
#define WS_RING  0x21000u   // u16[4][32][512] = 131072 B
#define WS_WHH   0x41000u   // u16[512*512] bf16 = 512 KB
#define WS_WIH   0xC1000u   // u16[64*512] bf16 = 64 KB
#define WS_W1T   0xD1000u   // u16[512*512] bf16 [n][k]
#define WS_ZERO  0x11000u   // memset span: covers flags only

__device__ __forceinline__ u16 f2bf(float f) {
  union { float f; unsigned int i; } x; x.f = f;
  unsigned int r = (x.i + 0x7FFFu + ((x.i >> 16) & 1u)) >> 16;
  return (u16)r;
}
__device__ __forceinline__ float bf2f(u16 u) {
  union { unsigned int i; float f; } x; x.i = ((unsigned int)u) << 16; return x.f;
}
__device__ __forceinline__ float sigmoidf_(float z) {
  return 1.0f / (1.0f + __expf(-z));
}

// ---------------------------------------------------------------------------
// Prep: fp32 -> bf16 copies (w_hh, w_ih layout-preserved; fc1_w transposed)
// ---------------------------------------------------------------------------
__global__ void prep_kernel(const float* __restrict__ whh,
                            const float* __restrict__ wih,
                            const float* __restrict__ w1,
                            u16* __restrict__ whh_bf,
                            u16* __restrict__ wih_bf,
                            u16* __restrict__ w1t_bf) {
  int idx = blockIdx.x * 256 + threadIdx.x;
  if (idx < 262144) {
    whh_bf[idx] = f2bf(whh[idx]);
  } else if (idx < 294912) {
    int i = idx - 262144;
    wih_bf[i] = f2bf(wih[i]);
  } else if (idx < 557056) {
    int j = idx - 294912;
    int n = j >> 9, k = j & 511;
    w1t_bf[n * Hz + k] = f2bf(w1[k * Hz + n]);  // [n][k] <- [k][n]
  }
}

// ---------------------------------------------------------------------------
// Scan R10 = R9 structure with the spill fixed.
// R9 post-mortem: __launch_bounds__(512,2) made the compiler target
// 2 blocks/CU -> 4 waves/SIMD -> 128-VGPR cap, spilling the 128-VGPR
// register-resident W_hh B-frag array to scratch; every K-step MFMA then
// reloaded its B operand from scratch on the critical path (dur 2x WORSE
// than R8 despite FETCH_SIZE dropping 165->26 MB as predicted).
// Fix: __launch_bounds__(512,1) -> 1 block/CU -> 256-VGPR cap; the ~220
// live VGPRs now fit with no spill.
//
// Structure (unchanged from R9): 4 blocks x 512 thr (8 waves).
// Recurrence is batch-row independent. Pair p = rows [16p,16p+16); block qh
// owns cols [256qh,256qh+256) and holds W_hh[:, own-cols] in registers
// (bhh[2][16] = 128 VGPR/wave). Per step only an 8 KB h-half is exchanged
// with ONE partner block (flag fan-in = 1).
//   - own-half K MFMAs read A-frags from LDS (written locally last step),
//     executed BEFORE the partner poll (hides compute under exchange).
//   - partner-half K MFMAs read A-frags DIRECTLY from the coherent ring
//     (16 u64 relaxed agent loads -> one pipelined L3 round trip).
// Protocol (proven): producer ring atomic-stores -> __syncthreads (drains
// own vmcnt) -> relaxed flag store -> plain output stores. Consumer:
// relaxed flag poll (exit only after load RETURNS 1) -> loads issued
// strictly later. Ring depth 4 + flag lockstep keeps slot reuse race-free.
// MFMA 16x16x32 bf16 (HW-proven): A m=lane&15,k=q*8+j; B n=lane&15,k=q*8+j;
//                                 C/D col=lane&15, row=q*4+reg.
// ---------------------------------------------------------------------------
__global__ __launch_bounds__(512, 1) void rnn_scan_kernel(
    const float* __restrict__ inp,   // [B][T][I] fp32
    const float* __restrict__ hn,    // [B][H] fp32
    const u16* __restrict__ whh_bf,  // [k=H][n=H] bf16
    const u16* __restrict__ wih_bf,  // [i=I][n=H] bf16
    float* __restrict__ out_rnn,     // [B][T][H] fp32
    float* __restrict__ out_hn,      // [B][H] fp32
    int* __restrict__ flags,         // [1025][NBLK] (zeroed)
    u16* __restrict__ hbuf)          // [4][B][H] bf16 ring
{
  // own-half h, double-buffered. Row stride 264 u16 = 528 B (multiple of 16
  // for ds_read_b128; +8 pad gives 4-bank/row shift to spread b128 groups).
  __shared__ u16 hlds[2][16][264];

  const int tid  = threadIdx.x;
  const int lane = tid & 63;
  const int w    = tid >> 6;        // wave 0..7 -> own cols [32w, 32w+32)
  const int ln   = lane & 15;
  const int q    = lane >> 4;
  const int bid  = blockIdx.x;
  const int qh   = bid & 1;         // col-half within pair
  const int p    = bid >> 1;        // pair index (row group)
  const int r0   = p * 16;          // global row base
  const int cbase = qh * 256;       // own col base
  const int obase = (1 - qh) * 256; // partner col base
  const int c0   = cbase + w * 32;  // wave's own col base
  const int partner = bid ^ 1;

  // ---- Preload W_hh B-frags for own cols, ALL K (ks 0..7 own-half K,
  // ks 8..15 partner-half K) : 2 tiles x 16 K-steps x 4 VGPR = 128 VGPR.
  bf16x8 bhh[2][16];
#pragma unroll
  for (int ct = 0; ct < 2; ++ct)
#pragma unroll
    for (int ks = 0; ks < 16; ++ks) {
      const int kg = (ks < 8) ? (cbase + ks * 32) : (obase + (ks - 8) * 32);
      u16x8 f;
#pragma unroll
      for (int j = 0; j < 8; ++j)
        f[j] = whh_bf[(kg + q * 8 + j) * Hz + c0 + ct * 16 + ln];
      bhh[ct][ks] = __builtin_bit_cast(bf16x8, f);
    }

  // ---- W_ih B-frags: 2 tiles x 2 K-steps (I=64)
  bf16x8 bih[2][2];
#pragma unroll
  for (int ct = 0; ct < 2; ++ct)
#pragma unroll
    for (int kc = 0; kc < 2; ++kc) {
      u16x8 f;
#pragma unroll
      for (int j = 0; j < 8; ++j)
        f[j] = wih_bf[(kc * 32 + q * 8 + j) * Hz + c0 + ct * 16 + ln];
      bih[ct][kc] = __builtin_bit_cast(bf16x8, f);
    }

  // ---- Init: h0 (own rows x own cols) -> LDS buf0 + ring slot 0
  {
    const int lrow = tid >> 5;          // 0..15
    const int cc   = (tid & 31) * 8;    // 0..248
    f32x4 a = *(const f32x4*)(hn + (size_t)(r0 + lrow) * Hz + cbase + cc);
    f32x4 b = *(const f32x4*)(hn + (size_t)(r0 + lrow) * Hz + cbase + cc + 4);
    u16x8 px;
#pragma unroll
    for (int j = 0; j < 4; ++j) { px[j] = f2bf(a[j]); px[4 + j] = f2bf(b[j]); }
    *(u16x8*)&hlds[0][lrow][cc] = px;
    u32* rp = (u32*)(hbuf + (size_t)(r0 + lrow) * Hz + cbase + cc);
#pragma unroll
    for (int k = 0; k < 4; ++k) {
      u32 pk = (u32)px[2 * k] | ((u32)px[2 * k + 1] << 16);
      __hip_atomic_store(rp + k, pk, __ATOMIC_RELAXED, __HIP_MEMORY_SCOPE_AGENT);
    }
  }
  __syncthreads();
  if (tid == 0)
    __hip_atomic_store(&flags[bid], 1, __ATOMIC_RELAXED,
                       __HIP_MEMORY_SCOPE_AGENT);

  for (int t = 0; t < Tz; ++t) {
    const int cur = t & 1;

    // inp loads for this step (HBM/L2, issued early)
    const float* ip = inp + ((size_t)(r0 + ln) * Tz + t) * Iz + q * 8;
    f32x4 x0 = *(const f32x4*)(ip);
    f32x4 x1 = *(const f32x4*)(ip + 4);
    f32x4 x2 = *(const f32x4*)(ip + 32);
    f32x4 x3 = *(const f32x4*)(ip + 36);
    u16x8 ax0, ax1;
#pragma unroll
    for (int j = 0; j < 4; ++j) {
      ax0[j]     = f2bf(x0[j]);
      ax0[4 + j] = f2bf(x1[j]);
      ax1[j]     = f2bf(x2[j]);
      ax1[4 + j] = f2bf(x3[j]);
    }

    f32x4 acc[2];
    acc[0] = (f32x4){0.f, 0.f, 0.f, 0.f};
    acc[1] = (f32x4){0.f, 0.f, 0.f, 0.f};

    // x-projection MFMAs
#pragma unroll
    for (int ct = 0; ct < 2; ++ct) {
      acc[ct] = __builtin_amdgcn_mfma_f32_16x16x32_bf16(
          __builtin_bit_cast(bf16x8, ax0), bih[ct][0], acc[ct], 0, 0, 0);
      acc[ct] = __builtin_amdgcn_mfma_f32_16x16x32_bf16(
          __builtin_bit_cast(bf16x8, ax1), bih[ct][1], acc[ct], 0, 0, 0);
    }

    // Phase A: own-half K from LDS (pre-poll; hides under partner exchange)
#pragma unroll
    for (int ks = 0; ks < 8; ++ks) {
      bf16x8 afr = __builtin_bit_cast(
          bf16x8, *(const u16x8*)&hlds[cur][ln][ks * 32 + q * 8]);
#pragma unroll
      for (int ct = 0; ct < 2; ++ct)
        acc[ct] = __builtin_amdgcn_mfma_f32_16x16x32_bf16(
            afr, bhh[ct][ks], acc[ct], 0, 0, 0);
    }

    // Poll single partner flag (wave-uniform address, all waves)
    {
      int got;
      do {
        got = __hip_atomic_load(&flags[t * NBLK + partner], __ATOMIC_RELAXED,
                                __HIP_MEMORY_SCOPE_AGENT);
      } while (!got);
    }

    // Phase B: partner-half A-frags straight from the coherent ring
    const u64* pb = (const u64*)hbuf + (size_t)(t & 3) * (Bz * Hz / 4) +
                    (size_t)(r0 + ln) * (Hz / 4) + (obase / 4);
    u64 hr[16];
#pragma unroll
    for (int ks2 = 0; ks2 < 8; ++ks2) {
      hr[2 * ks2]     = __hip_atomic_load(pb + ks2 * 8 + q * 2,
                                          __ATOMIC_RELAXED,
                                          __HIP_MEMORY_SCOPE_AGENT);
      hr[2 * ks2 + 1] = __hip_atomic_load(pb + ks2 * 8 + q * 2 + 1,
                                          __ATOMIC_RELAXED,
                                          __HIP_MEMORY_SCOPE_AGENT);
    }
#pragma unroll
    for (int ks2 = 0; ks2 < 8; ++ks2) {
      u64 v[2] = {hr[2 * ks2], hr[2 * ks2 + 1]};
      bf16x8 afr = __builtin_bit_cast(bf16x8, v);
#pragma unroll
      for (int ct = 0; ct < 2; ++ct)
        acc[ct] = __builtin_amdgcn_mfma_f32_16x16x32_bf16(
            afr, bhh[ct][8 + ks2], acc[ct], 0, 0, 0);
    }

    // Epilogue: sigmoid; pack pairs; ring store + LDS store (next buffer)
    const int nxt = cur ^ 1;
    u16* ring_next = hbuf + (size_t)((t + 1) & 3) * (Bz * Hz);
    float hv[2][4];
#pragma unroll
    for (int ct = 0; ct < 2; ++ct)
#pragma unroll
      for (int r = 0; r < 4; ++r) {
        hv[ct][r] = sigmoidf_(acc[ct][r]);
        u32 mine  = (u32)f2bf(hv[ct][r]);
        u32 other = (u32)__shfl_xor((int)mine, 1, 64);
        if (!(ln & 1)) {
          u32 pk = mine | (other << 16);
          const int lrow = q * 4 + r;
          const int lcol = w * 32 + ct * 16 + ln;  // within own 256-col half
          __hip_atomic_store(
              (u32*)(ring_next + (size_t)(r0 + lrow) * Hz + cbase + lcol), pk,
              __ATOMIC_RELAXED, __HIP_MEMORY_SCOPE_AGENT);
          *(u32*)&hlds[nxt][lrow][lcol] = pk;
        }
      }
    __syncthreads();  // drains every thread's ring/LDS stores before flag
    if (tid == 0)
      __hip_atomic_store(&flags[(t + 1) * NBLK + bid], 1, __ATOMIC_RELAXED,
                         __HIP_MEMORY_SCOPE_AGENT);

    // Output stores AFTER the flag release — off the critical path
#pragma unroll
    for (int ct = 0; ct < 2; ++ct)
#pragma unroll
      for (int r = 0; r < 4; ++r) {
        const int grow = r0 + q * 4 + r;
        const int gcol = c0 + ct * 16 + ln;
        out_rnn[((size_t)grow * Tz + t) * Hz + gcol] = hv[ct][r];
        if (t == Tz - 1) out_hn[(size_t)grow * Hz + gcol] = hv[ct][r];
      }
  }
}

// ---------------------------------------------------------------------------
// FC head (unchanged, R3-lineage): 256 blocks x 256 thr; fc1 MFMA bf16
// (tile 128x128, BK=64); hidden via LDS; fc2 VALU-accumulated; fp32 in/out.
// ---------------------------------------------------------------------------
__global__ __launch_bounds__(256, 2) void fc_kernel(
    const float* __restrict__ X,  // [32768][512] fp32 (= rnn_out)
    const u16* __restrict__ w1t,  // [n=512][k=512] bf16
    const float* __restrict__ b1, // [512] fp32
    const float* __restrict__ w2, // [n=512][a=16] fp32
    const float* __restrict__ b2, // [16] fp32
    float* __restrict__ out)      // [32768][16] fp32
{
  __shared__ u16 smem[18432];     // 36 KB
  u16* As = smem;                 // [128][72]
  u16* Bs = smem + 9216;          // [128][72]
  u16* Ht = smem;                 // [128][136] (reused, 34816 B)

  const int tid  = threadIdx.x;
  const int lane = tid & 63;
  const int wv   = tid >> 6;
  const int ln   = lane & 15, q = lane >> 4;
  const int mq   = (wv & 1) * 64, nq = (wv >> 1) * 64;
  const size_t r0 = (size_t)blockIdx.x * 128;
  const int om = tid >> 1;          // output row 0..127
  const int oa = (tid & 1) * 8;     // output col half

  float oacc[8];
#pragma unroll
  for (int j = 0; j < 8; ++j) oacc[j] = 0.f;

  for (int nt = 0; nt < 4; ++nt) {
    const int n0 = nt * 128;
    f32x4 acc[4][4];
#pragma unroll
    for (int mi = 0; mi < 4; ++mi)
#pragma unroll
      for (int ni = 0; ni < 4; ++ni) acc[mi][ni] = (f32x4){0.f, 0.f, 0.f, 0.f};

    for (int kb = 0; kb < 8; ++kb) {
      const int K0 = kb * 64;
      __syncthreads();  // prior frag/Ht reads done before restaging
      for (int i = tid; i < 1024; i += 256) {
        int row = i >> 3, c = (i & 7) * 8;
        f32x4 lo = *(const f32x4*)(X + (r0 + row) * Hz + K0 + c);
        f32x4 hi = *(const f32x4*)(X + (r0 + row) * Hz + K0 + c + 4);
        u16x8 pxx;
#pragma unroll
        for (int j = 0; j < 4; ++j) { pxx[j] = f2bf(lo[j]); pxx[4 + j] = f2bf(hi[j]); }
        *(u16x8*)(As + row * 72 + c) = pxx;
      }
      for (int i = tid; i < 1024; i += 256) {
        int row = i >> 3, c = (i & 7) * 8;
        *(u16x8*)(Bs + row * 72 + c) =
            *(const u16x8*)(w1t + (size_t)(n0 + row) * Hz + K0 + c);
      }
      __syncthreads();
#pragma unroll
      for (int kt = 0; kt < 2; ++kt) {
        bf16x8 af[4], bfr[4];
#pragma unroll
        for (int mi = 0; mi < 4; ++mi)
          af[mi] = __builtin_bit_cast(
              bf16x8,
              *(const u16x8*)(As + (mq + mi * 16 + ln) * 72 + kt * 32 + q * 8));
#pragma unroll
        for (int ni = 0; ni < 4; ++ni)
          bfr[ni] = __builtin_bit_cast(
              bf16x8,
              *(const u16x8*)(Bs + (nq + ni * 16 + ln) * 72 + kt * 32 + q * 8));
#pragma unroll
        for (int mi = 0; mi < 4; ++mi)
#pragma unroll
          for (int ni = 0; ni < 4; ++ni)
            acc[mi][ni] = __builtin_amdgcn_mfma_f32_16x16x32_bf16(
                af[mi], bfr[ni], acc[mi][ni], 0, 0, 0);
      }
    }
    __syncthreads();  // MFMA frag reads done before Ht overwrite

    // hidden = relu(acc + b1) -> Ht bf16
#pragma unroll
    for (int ni = 0; ni < 4; ++ni) {
      float bb = b1[n0 + nq + ni * 16 + ln];
#pragma unroll
      for (int mi = 0; mi < 4; ++mi)
#pragma unroll
        for (int r = 0; r < 4; ++r) {
          float h = fmaxf(acc[mi][ni][r] + bb, 0.f);
          Ht[(mq + mi * 16 + q * 4 + r) * 136 + nq + ni * 16 + ln] = f2bf(h);
        }
    }
    __syncthreads();

    // fc2 partial over this n-slice into registers
    for (int n = 0; n < 128; ++n) {
      float hv = bf2f(Ht[om * 136 + n]);
      const float* w2p = w2 + (size_t)(n0 + n) * Az + oa;
#pragma unroll
      for (int j = 0; j < 8; ++j) oacc[j] += hv * w2p[j];
    }
  }

#pragma unroll
  for (int j = 0; j < 8; ++j)
    out[(r0 + om) * Az + oa + j] = sigmoidf_(oacc[j] + b2[oa + j]);
}

extern "C" void kernel_launch(void* const* d_in, const int* in_sizes, int n_in,
                              void* d_out, int out_size, void* d_ws, size_t ws_size,
                              hipStream_t stream) {
  // Permutation detection from in_sizes (insurance; proven harmless R6/R7)
  int idx_inp = 0, idx_hn = 1, idx_wih = 3, idx_b1 = 5, idx_w2 = 6, idx_b2 = 7;
  int amb1 = -1, amb2 = -1, found = 0;
  for (int i = 0; i < 8 && i < n_in; ++i) {
    switch (in_sizes[i]) {
      case 2097152: idx_inp = i; found |= 1; break;
      case 16384:   idx_hn  = i; found |= 2; break;
      case 32768:   idx_wih = i; found |= 4; break;
      case 512:     idx_b1  = i; found |= 8; break;
      case 8192:    idx_w2  = i; found |= 16; break;
      case 16:      idx_b2  = i; found |= 32; break;
      case 262144:  if (amb1 < 0) amb1 = i; else amb2 = i; break;
    }
  }
  int idx_whh = 2, idx_w1 = 4;  // dict-order fallback
  if (amb1 >= 0 && amb2 >= 0 && found == 63) {
    if (idx_b1 < idx_inp) { idx_w1 = amb1; idx_whh = amb2; }
    else                  { idx_whh = amb1; idx_w1 = amb2; }
  }

  const float* inp = (const float*)d_in[idx_inp];
  const float* hn  = (const float*)d_in[idx_hn];
  const float* whh = (const float*)d_in[idx_whh];
  const float* wih = (const float*)d_in[idx_wih];
  const float* w1  = (const float*)d_in[idx_w1];
  const float* b1  = (const float*)d_in[idx_b1];
  const float* w2  = (const float*)d_in[idx_w2];
  const float* b2  = (const float*)d_in[idx_b2];

  float* out     = (float*)d_out;
  float* out_hn  = out + OFF_HN;
  float* out_rnn = out + OFF_RNN;

  char* ws    = (char*)d_ws;
  int* flags  = (int*)(ws + WS_FLAGS);
  u16* hbuf   = (u16*)(ws + WS_RING);
  u16* whh_bf = (u16*)(ws + WS_WHH);
  u16* wih_bf = (u16*)(ws + WS_WIH);
  u16* w1t_bf = (u16*)(ws + WS_W1T);

  (void)hipMemsetAsync(d_ws, 0, WS_ZERO, stream);
  prep_kernel<<<dim3(2176), dim3(256), 0, stream>>>(whh, wih, w1,
                                                    whh_bf, wih_bf, w1t_bf);
  rnn_scan_kernel<<<dim3(NBLK), dim3(512), 0, stream>>>(
      inp, hn, whh_bf, wih_bf, out_rnn, out_hn, flags, hbuf);
  fc_kernel<<<dim3(256), dim3(256), 0, stream>>>(
      out_rnn, w1t_bf, b1, w2, b2, out);
}

// Round 6
// 3725.167 us; speedup vs baseline: 1.8245x; 1.8245x over previous
//
#include <hip/hip_runtime.h>
#include <hip/hip_bf16.h>

#define Bz 32
#define Tz 1024
#define Iz 64
#define Hz 512
#define Az 16

// d_out layout (FP32 elems): out [B,T,A] | hn [1,B,H] | rnn_out [B,T,H]
#define OFF_HN  (Bz*Tz*Az)
#define OFF_RNN (OFF_HN + Bz*Hz)

typedef unsigned short u16;
typedef unsigned int u32;
typedef unsigned long long u64;
typedef __attribute__((ext_vector_type(8))) unsigned short u16x8;
typedef __attribute__((ext_vector_type(8))) __bf16 bf16x8;
typedef __attribute__((ext_vector_type(4))) float f32x4;

// ws layout (bytes) — no flags, no ring (zero inter-block communication)
#define WS_WIH  0x00000u  // u16[64*512] bf16 (layout-preserved)      = 64 KB
#define WS_WHT  0x10000u  // u16[512*512] bf16 whhT [n][k]            = 512 KB
#define WS_W1T  0x90000u  // u16[512*512] bf16 w1t [n][k]; end 0x110000

__device__ __forceinline__ u16 f2bf(float f) {
  union { float f; unsigned int i; } x; x.f = f;
  unsigned int r = (x.i + 0x7FFFu + ((x.i >> 16) & 1u)) >> 16;
  return (u16)r;
}
__device__ __forceinline__ float bf2f(u16 u) {
  union { unsigned int i; float f; } x; x.i = ((unsigned int)u) << 16; return x.f;
}
__device__ __forceinline__ float sigmoidf_(float z) {
  return 1.0f / (1.0f + __expf(-z));
}

// ---------------------------------------------------------------------------
// Prep: fp32 -> bf16 copies. whhT and w1t TRANSPOSED to [n][k] (coalesced
// writes, scattered reads through L2); wih layout-preserved.
// ---------------------------------------------------------------------------
__global__ void prep_kernel(const float* __restrict__ whh,
                            const float* __restrict__ wih,
                            const float* __restrict__ w1,
                            u16* __restrict__ whhT,
                            u16* __restrict__ wih_bf,
                            u16* __restrict__ w1t_bf) {
  int idx = blockIdx.x * 256 + threadIdx.x;
  if (idx < 262144) {
    int n = idx >> 9, k = idx & 511;
    whhT[idx] = f2bf(whh[k * Hz + n]);        // whhT[n][k] <- whh[k][n]
  } else if (idx < 294912) {
    int i = idx - 262144;
    wih_bf[i] = f2bf(wih[i]);
  } else if (idx < 557056) {
    int j = idx - 294912;
    int n = j >> 9, k = j & 511;
    w1t_bf[n * Hz + k] = f2bf(w1[k * Hz + n]);  // [n][k] <- [k][n]
  }
}

// ---------------------------------------------------------------------------
// xproj: out_rnn[b*T+t][n] = sum_i inp[b][t][i] * wih[i][n]  (fp32 result).
// The scan reads this per step and overwrites it in place with h_t — no
// extra workspace. 512 blocks x 256 thr (4 waves x 16 rows); W_ih staged
// col-major in LDS; MFMA 16x16x32 bf16 (proven fragment maps).
// ---------------------------------------------------------------------------
__global__ __launch_bounds__(256, 2) void xproj_kernel(
    const float* __restrict__ inp,   // [32768 rows][64]
    const u16* __restrict__ wih_bf,  // [i=64][n=512]
    float* __restrict__ xp)          // [32768][512] (= out_rnn region)
{
  __shared__ u16 wl[512][72];  // col-major [n][i], pad 8 -> 73,728 B

  const int tid  = threadIdx.x;
  const int lane = tid & 63;
  const int wv   = tid >> 6;
  const int ln   = lane & 15;
  const int q    = lane >> 4;

  // stage W_ih transposed: per i, 256 threads read coalesced
#pragma unroll
  for (int i = 0; i < Iz; ++i) {
    wl[tid][i]       = wih_bf[i * Hz + tid];
    wl[tid + 256][i] = wih_bf[i * Hz + tid + 256];
  }
  __syncthreads();

  const size_t row0 = (size_t)blockIdx.x * 64 + wv * 16;
  const float* ip = inp + (row0 + ln) * Iz + q * 8;
  f32x4 x0 = *(const f32x4*)(ip);
  f32x4 x1 = *(const f32x4*)(ip + 4);
  f32x4 x2 = *(const f32x4*)(ip + 32);
  f32x4 x3 = *(const f32x4*)(ip + 36);
  u16x8 ax0, ax1;
#pragma unroll
  for (int j = 0; j < 4; ++j) {
    ax0[j]     = f2bf(x0[j]);
    ax0[4 + j] = f2bf(x1[j]);
    ax1[j]     = f2bf(x2[j]);
    ax1[4 + j] = f2bf(x3[j]);
  }

  for (int nt = 0; nt < 32; ++nt) {
    bf16x8 b0 = __builtin_bit_cast(bf16x8, *(const u16x8*)&wl[nt * 16 + ln][q * 8]);
    bf16x8 b1 = __builtin_bit_cast(bf16x8, *(const u16x8*)&wl[nt * 16 + ln][32 + q * 8]);
    f32x4 a = {0.f, 0.f, 0.f, 0.f};
    a = __builtin_amdgcn_mfma_f32_16x16x32_bf16(
        __builtin_bit_cast(bf16x8, ax0), b0, a, 0, 0, 0);
    a = __builtin_amdgcn_mfma_f32_16x16x32_bf16(
        __builtin_bit_cast(bf16x8, ax1), b1, a, 0, 0, 0);
#pragma unroll
    for (int r = 0; r < 4; ++r)
      xp[(row0 + q * 4 + r) * Hz + nt * 16 + ln] = a[r];
  }
}

// ---------------------------------------------------------------------------
// Scan R12 = R11 with the wlds staging bug fixed.
// R11 post-mortem: the W-LDS staging loop strided 16 ELEMENTS per iteration
// but u16x8 stores cover only 8 elements -> half of wlds was uninitialized
// garbage and half of W_hh k in [384,512) was never staged (absmax 0.248).
// Fix: 16 iterations x stride 8. Everything else byte-identical to R11.
//
// Design: 2 blocks x 512 thr (8 waves). ZERO inter-block communication
// (R10 showed the agent-scope exchange path caps at ~4 B/cyc/CU and every
// prior round's step time == coherent bytes / that rate). Batch-row
// partitioning: block p owns rows [16p,16p+16); h lives in block-local LDS.
// W_hh (512 KB) fully resident per CU:
//   - k in [0,384): B-frags in registers/AGPRs, bhh[4 ct][12 ks]
//   - k in [384,512): B-frags in LDS, col-major wlds[512][136]
// x-projection precomputed by xproj_kernel into out_rnn; scan loads xp[t]
// (issued at step top, consumed at epilogue), adds before sigmoid, and
// overwrites the same location with h_t (same lane reads & writes).
// MFMA 16x16x32 bf16 (HW-proven): A m=lane&15,k=q*8+j; B n=lane&15,k=q*8+j;
//                                 C/D col=lane&15, row=q*4+reg.
// ---------------------------------------------------------------------------
__global__ __launch_bounds__(512, 2) void rnn_scan_kernel(
    const float* __restrict__ hn,    // [B][H] fp32
    const u16* __restrict__ whhT,    // [n=H][k=H] bf16
    float* __restrict__ out_rnn,     // [B][T][H] fp32, pre-filled with xproj
    float* __restrict__ out_hn)      // [B][H] fp32
{
  __shared__ u16 wlds[512][136];  // W_hh k in [384,512), col-major: 139,264 B
  __shared__ u16 hlds[16][528];   // h_t [row][gcol], pad 16:        16,896 B

  const int tid  = threadIdx.x;
  const int lane = tid & 63;
  const int w    = tid >> 6;      // wave 0..7 -> cols [64w, 64w+64)
  const int ln   = lane & 15;
  const int q    = lane >> 4;
  const int r0   = blockIdx.x * 16;
  const int c0   = w * 64;

  // ---- W_hh k in [0,384) -> registers (16-B vector loads from whhT[n][k])
  bf16x8 bhh[4][12];
#pragma unroll
  for (int ct = 0; ct < 4; ++ct)
#pragma unroll
    for (int ks = 0; ks < 12; ++ks)
      bhh[ct][ks] = __builtin_bit_cast(
          bf16x8, *(const u16x8*)(whhT + (size_t)(c0 + ct * 16 + ln) * Hz +
                                  ks * 32 + q * 8));

  // ---- W_hh k in [384,512) -> LDS (col = tid; 16 x u16x8 = 128 elements)
  // R11 BUG WAS HERE: stride was 16 elems with 8-elem stores. Now 16 x 8.
#pragma unroll
  for (int j = 0; j < 16; ++j)
    *(u16x8*)&wlds[tid][j * 8] =
        *(const u16x8*)(whhT + (size_t)tid * Hz + 384 + j * 8);

  // ---- h0 -> LDS
  {
    const int row = tid >> 5, c = (tid & 31) * 16;
    const float* hp = hn + (size_t)(r0 + row) * Hz + c;
    f32x4 a0 = *(const f32x4*)(hp);
    f32x4 a1 = *(const f32x4*)(hp + 4);
    f32x4 a2 = *(const f32x4*)(hp + 8);
    f32x4 a3 = *(const f32x4*)(hp + 12);
    u16x8 p0, p1;
#pragma unroll
    for (int j = 0; j < 4; ++j) {
      p0[j] = f2bf(a0[j]); p0[4 + j] = f2bf(a1[j]);
      p1[j] = f2bf(a2[j]); p1[4 + j] = f2bf(a3[j]);
    }
    *(u16x8*)&hlds[row][c]     = p0;
    *(u16x8*)&hlds[row][c + 8] = p1;
  }
  __syncthreads();

  for (int t = 0; t < Tz; ++t) {
    // xp loads issued first — consumed ~1000 cyc later (latency hidden)
    float xp[4][4];
#pragma unroll
    for (int r = 0; r < 4; ++r) {
      const float* xrow =
          out_rnn + ((size_t)(r0 + q * 4 + r) * Tz + t) * Hz + c0 + ln;
#pragma unroll
      for (int ct = 0; ct < 4; ++ct) xp[ct][r] = xrow[ct * 16];
    }

    f32x4 acc[4];
#pragma unroll
    for (int ct = 0; ct < 4; ++ct) acc[ct] = (f32x4){0.f, 0.f, 0.f, 0.f};

    // k in [0,384): A from h-LDS, B from registers
#pragma unroll
    for (int ks = 0; ks < 12; ++ks) {
      bf16x8 A = __builtin_bit_cast(
          bf16x8, *(const u16x8*)&hlds[ln][ks * 32 + q * 8]);
#pragma unroll
      for (int ct = 0; ct < 4; ++ct)
        acc[ct] = __builtin_amdgcn_mfma_f32_16x16x32_bf16(
            A, bhh[ct][ks], acc[ct], 0, 0, 0);
    }
    // k in [384,512): A from h-LDS, B from W-LDS
#pragma unroll
    for (int lk = 0; lk < 4; ++lk) {
      bf16x8 A = __builtin_bit_cast(
          bf16x8, *(const u16x8*)&hlds[ln][(12 + lk) * 32 + q * 8]);
#pragma unroll
      for (int ct = 0; ct < 4; ++ct) {
        bf16x8 Bf = __builtin_bit_cast(
            bf16x8, *(const u16x8*)&wlds[c0 + ct * 16 + ln][lk * 32 + q * 8]);
        acc[ct] = __builtin_amdgcn_mfma_f32_16x16x32_bf16(
            A, Bf, acc[ct], 0, 0, 0);
      }
    }

    // h = sigmoid(acc + xp)
    float hv[4][4];
#pragma unroll
    for (int ct = 0; ct < 4; ++ct)
#pragma unroll
      for (int r = 0; r < 4; ++r) hv[ct][r] = sigmoidf_(acc[ct][r] + xp[ct][r]);

    __syncthreads();  // all waves' h_t A-reads complete before overwrite

    // write h_{t+1} into h-LDS (pack bf16 pairs, even lanes store u32)
#pragma unroll
    for (int ct = 0; ct < 4; ++ct)
#pragma unroll
      for (int r = 0; r < 4; ++r) {
        u32 mine  = (u32)f2bf(hv[ct][r]);
        u32 other = (u32)__shfl_xor((int)mine, 1, 64);
        if (!(ln & 1))
          *(u32*)&hlds[q * 4 + r][c0 + ct * 16 + ln] = mine | (other << 16);
      }
    __syncthreads();  // h_{t+1} visible to all waves

    // overwrite the xp slot with h (off critical path; drains next step)
#pragma unroll
    for (int r = 0; r < 4; ++r) {
      float* orow =
          out_rnn + ((size_t)(r0 + q * 4 + r) * Tz + t) * Hz + c0 + ln;
#pragma unroll
      for (int ct = 0; ct < 4; ++ct) orow[ct * 16] = hv[ct][r];
    }
    if (t == Tz - 1) {
#pragma unroll
      for (int r = 0; r < 4; ++r)
#pragma unroll
        for (int ct = 0; ct < 4; ++ct)
          out_hn[(size_t)(r0 + q * 4 + r) * Hz + c0 + ct * 16 + ln] = hv[ct][r];
    }
  }
}

// ---------------------------------------------------------------------------
// FC head (unchanged, R3-lineage): 256 blocks x 256 thr; fc1 MFMA bf16
// (tile 128x128, BK=64); hidden via LDS; fc2 VALU-accumulated; fp32 in/out.
// ---------------------------------------------------------------------------
__global__ __launch_bounds__(256, 2) void fc_kernel(
    const float* __restrict__ X,  // [32768][512] fp32 (= rnn_out)
    const u16* __restrict__ w1t,  // [n=512][k=512] bf16
    const float* __restrict__ b1, // [512] fp32
    const float* __restrict__ w2, // [n=512][a=16] fp32
    const float* __restrict__ b2, // [16] fp32
    float* __restrict__ out)      // [32768][16] fp32
{
  __shared__ u16 smem[18432];     // 36 KB
  u16* As = smem;                 // [128][72]
  u16* Bs = smem + 9216;          // [128][72]
  u16* Ht = smem;                 // [128][136] (reused, 34816 B)

  const int tid  = threadIdx.x;
  const int lane = tid & 63;
  const int wv   = tid >> 6;
  const int ln   = lane & 15, q = lane >> 4;
  const int mq   = (wv & 1) * 64, nq = (wv >> 1) * 64;
  const size_t r0 = (size_t)blockIdx.x * 128;
  const int om = tid >> 1;          // output row 0..127
  const int oa = (tid & 1) * 8;     // output col half

  float oacc[8];
#pragma unroll
  for (int j = 0; j < 8; ++j) oacc[j] = 0.f;

  for (int nt = 0; nt < 4; ++nt) {
    const int n0 = nt * 128;
    f32x4 acc[4][4];
#pragma unroll
    for (int mi = 0; mi < 4; ++mi)
#pragma unroll
      for (int ni = 0; ni < 4; ++ni) acc[mi][ni] = (f32x4){0.f, 0.f, 0.f, 0.f};

    for (int kb = 0; kb < 8; ++kb) {
      const int K0 = kb * 64;
      __syncthreads();  // prior frag/Ht reads done before restaging
      for (int i = tid; i < 1024; i += 256) {
        int row = i >> 3, c = (i & 7) * 8;
        f32x4 lo = *(const f32x4*)(X + (r0 + row) * Hz + K0 + c);
        f32x4 hi = *(const f32x4*)(X + (r0 + row) * Hz + K0 + c + 4);
        u16x8 pxx;
#pragma unroll
        for (int j = 0; j < 4; ++j) { pxx[j] = f2bf(lo[j]); pxx[4 + j] = f2bf(hi[j]); }
        *(u16x8*)(As + row * 72 + c) = pxx;
      }
      for (int i = tid; i < 1024; i += 256) {
        int row = i >> 3, c = (i & 7) * 8;
        *(u16x8*)(Bs + row * 72 + c) =
            *(const u16x8*)(w1t + (size_t)(n0 + row) * Hz + K0 + c);
      }
      __syncthreads();
#pragma unroll
      for (int kt = 0; kt < 2; ++kt) {
        bf16x8 af[4], bfr[4];
#pragma unroll
        for (int mi = 0; mi < 4; ++mi)
          af[mi] = __builtin_bit_cast(
              bf16x8,
              *(const u16x8*)(As + (mq + mi * 16 + ln) * 72 + kt * 32 + q * 8));
#pragma unroll
        for (int ni = 0; ni < 4; ++ni)
          bfr[ni] = __builtin_bit_cast(
              bf16x8,
              *(const u16x8*)(Bs + (nq + ni * 16 + ln) * 72 + kt * 32 + q * 8));
#pragma unroll
        for (int mi = 0; mi < 4; ++mi)
#pragma unroll
          for (int ni = 0; ni < 4; ++ni)
            acc[mi][ni] = __builtin_amdgcn_mfma_f32_16x16x32_bf16(
                af[mi], bfr[ni], acc[mi][ni], 0, 0, 0);
      }
    }
    __syncthreads();  // MFMA frag reads done before Ht overwrite

    // hidden = relu(acc + b1) -> Ht bf16
#pragma unroll
    for (int ni = 0; ni < 4; ++ni) {
      float bb = b1[n0 + nq + ni * 16 + ln];
#pragma unroll
      for (int mi = 0; mi < 4; ++mi)
#pragma unroll
        for (int r = 0; r < 4; ++r) {
          float h = fmaxf(acc[mi][ni][r] + bb, 0.f);
          Ht[(mq + mi * 16 + q * 4 + r) * 136 + nq + ni * 16 + ln] = f2bf(h);
        }
    }
    __syncthreads();

    // fc2 partial over this n-slice into registers
    for (int n = 0; n < 128; ++n) {
      float hv = bf2f(Ht[om * 136 + n]);
      const float* w2p = w2 + (size_t)(n0 + n) * Az + oa;
#pragma unroll
      for (int j = 0; j < 8; ++j) oacc[j] += hv * w2p[j];
    }
  }

#pragma unroll
  for (int j = 0; j < 8; ++j)
    out[(r0 + om) * Az + oa + j] = sigmoidf_(oacc[j] + b2[oa + j]);
}

extern "C" void kernel_launch(void* const* d_in, const int* in_sizes, int n_in,
                              void* d_out, int out_size, void* d_ws, size_t ws_size,
                              hipStream_t stream) {
  // Permutation detection from in_sizes (insurance; proven harmless R6/R7)
  int idx_inp = 0, idx_hn = 1, idx_wih = 3, idx_b1 = 5, idx_w2 = 6, idx_b2 = 7;
  int amb1 = -1, amb2 = -1, found = 0;
  for (int i = 0; i < 8 && i < n_in; ++i) {
    switch (in_sizes[i]) {
      case 2097152: idx_inp = i; found |= 1; break;
      case 16384:   idx_hn  = i; found |= 2; break;
      case 32768:   idx_wih = i; found |= 4; break;
      case 512:     idx_b1  = i; found |= 8; break;
      case 8192:    idx_w2  = i; found |= 16; break;
      case 16:      idx_b2  = i; found |= 32; break;
      case 262144:  if (amb1 < 0) amb1 = i; else amb2 = i; break;
    }
  }
  int idx_whh = 2, idx_w1 = 4;  // dict-order fallback
  if (amb1 >= 0 && amb2 >= 0 && found == 63) {
    if (idx_b1 < idx_inp) { idx_w1 = amb1; idx_whh = amb2; }
    else                  { idx_whh = amb1; idx_w1 = amb2; }
  }

  const float* inp = (const float*)d_in[idx_inp];
  const float* hn  = (const float*)d_in[idx_hn];
  const float* whh = (const float*)d_in[idx_whh];
  const float* wih = (const float*)d_in[idx_wih];
  const float* w1  = (const float*)d_in[idx_w1];
  const float* b1  = (const float*)d_in[idx_b1];
  const float* w2  = (const float*)d_in[idx_w2];
  const float* b2  = (const float*)d_in[idx_b2];

  float* out     = (float*)d_out;
  float* out_hn  = out + OFF_HN;
  float* out_rnn = out + OFF_RNN;

  char* ws    = (char*)d_ws;
  u16* wih_bf = (u16*)(ws + WS_WIH);
  u16* whhT   = (u16*)(ws + WS_WHT);
  u16* w1t_bf = (u16*)(ws + WS_W1T);

  prep_kernel<<<dim3(2176), dim3(256), 0, stream>>>(whh, wih, w1,
                                                    whhT, wih_bf, w1t_bf);
  xproj_kernel<<<dim3(512), dim3(256), 0, stream>>>(inp, wih_bf, out_rnn);
  rnn_scan_kernel<<<dim3(2), dim3(512), 0, stream>>>(
      hn, whhT, out_rnn, out_hn);
  fc_kernel<<<dim3(256), dim3(256), 0, stream>>>(
      out_rnn, w1t_bf, b1, w2, b2, out);
}